// Round 5
// baseline (113.142 us; speedup 1.0000x reference)
//
#include <hip/hip_runtime.h>
#include <cstdint>

#define NB   32
#define CIN  128
#define HH   56
#define WW   56
#define KOUT 256
#define HWS  (HH*WW)            // 3136
#define NHW  (NB*HWS)           // 100352
#define PADH 58                 // rows -1..56 -> 0..57 (0 and 57 are zero pad)
#define XCNT ((float)(NB*CIN*HWS))
#define WCNT ((float)(KOUT*CIN*9))

// Zero sums + zero the 2 pad rows per image (3584 uint4). Grid 14 x 256.
__global__ __launch_bounds__(256) void init_kernel(uint4* __restrict__ xpad,
                                                   float* __restrict__ sums) {
    int idx = blockIdx.x * 256 + threadIdx.x;        // 0..3583
    if (idx < 2) sums[idx] = 0.0f;
    int n = idx / 112, rem = idx - n * 112;
    int prow = (rem < 56) ? 0 : 57;
    int w = rem % 56;
    xpad[(n * PADH + prow) * WW + w] = make_uint4(0, 0, 0, 0);
}

__device__ __forceinline__ void block_reduce_add(float v, float* dst) {
    #pragma unroll
    for (int off = 32; off > 0; off >>= 1) v += __shfl_down(v, off);
    __shared__ float ws4[4];
    int lane = threadIdx.x & 63, wid = threadIdx.x >> 6;
    if (lane == 0) ws4[wid] = v;
    __syncthreads();
    if (threadIdx.x == 0) {
        float s = ws4[0];
        int nw = (blockDim.x + 63) >> 6;
        for (int i = 1; i < nw; i++) s += ws4[i];
        atomicAdd(dst, s);
    }
}

// Thread per (spatial idx, 32-channel word j); writes into PADDED layout.
__global__ __launch_bounds__(256) void pack_x_kernel(const float* __restrict__ x,
                                                     uint32_t* __restrict__ xpadw,
                                                     float* __restrict__ sums) {
    int j   = blockIdx.x / (NHW / 256);              // 0..3, uniform per block
    int idx = (blockIdx.x - j * (NHW / 256)) * 256 + threadIdx.x;
    int n  = idx / HWS;
    int hw = idx - n * HWS;
    int h  = hw / WW;
    int w  = hw - h * WW;
    const float* p = x + (size_t)n * CIN * HWS + (size_t)(j * 32) * HWS + hw;
    float asum = 0.0f;
    uint32_t bits = 0;
    #pragma unroll
    for (int t = 0; t < 32; t++) {
        float v = p[(size_t)t * HWS];
        asum += fabsf(v);
        bits |= (v > 0.0f ? 1u : 0u) << t;
    }
    xpadw[(((n * PADH + h + 1) * WW + w) << 2) + j] = bits;
    block_reduce_add(asum, &sums[0]);
}

// Thread per (k, tap, word j): block = (tap, j) [36 blocks], lane = k (256).
__global__ __launch_bounds__(256) void pack_w_kernel(const float* __restrict__ wgt,
                                                     uint32_t* __restrict__ wpackTw,
                                                     float* __restrict__ sums) {
    int k   = threadIdx.x;
    int tap = blockIdx.x >> 2;
    int j   = blockIdx.x & 3;
    const float* p = wgt + (size_t)k * CIN * 9 + (size_t)(j * 32) * 9 + tap;
    float asum = 0.0f;
    uint32_t bits = 0;
    #pragma unroll
    for (int t = 0; t < 32; t++) {
        float v = p[(size_t)t * 9];
        asum += fabsf(v);
        bits |= (v > 0.0f ? 1u : 0u) << t;
    }
    wpackTw[(tap * KOUT + k) * 4 + j] = bits;
    block_reduce_add(asum, &sums[1]);
}

// 1-wave block per (n, h, kgroup). lane = k within group. No barriers.
// x columns read straight from global (padded rows = real zeros) into a
// 4-slot register rotation, prefetch distance 2 bodies, static slot indices.
// Pad COLUMNS handled algebraically (cs0/cs2 folded into F0/F55).
__global__ __launch_bounds__(64, 4) void conv_kernel(const uint4* __restrict__ xpad,
                                                     const uint4* __restrict__ wpackT,
                                                     const float* __restrict__ sums,
                                                     const float* __restrict__ bias,
                                                     float* __restrict__ out) {
    __shared__ float sbuf[64 * 10];

    int l   = threadIdx.x;
    int bid = blockIdx.x;                 // (n*56 + h)*4 + kg  (kg fastest: L2 tile reuse)
    int kg  = bid & 3;
    int nh  = bid >> 2;
    int n   = nh / HH, h = nh - n * HH;
    int k   = kg * 64 + l;

    uint4 wq[9];
    #pragma unroll
    for (int t = 0; t < 9; t++) wq[t] = wpackT[t * KOUT + k];

    // base of the 3-row window (padded rows h, h+1, h+2 = hy h-1,h,h+1)
    const uint4* P = xpad + (size_t)(n * PADH + h) * WW;

    uint4 xs[4][3];   // slot s holds column rw with rw % 4 == s
#define PF(S, OFF) { xs[S][0] = PB[OFF]; xs[S][1] = PB[56 + (OFF)]; xs[S][2] = PB[112 + (OFF)]; }
    {
        const uint4* PB = P;
        PF(0, 0) PF(1, 1) PF(2, 2) PF(3, 3)
    }

    float scale = (sums[0] * (1.0f / XCNT)) * (sums[1] * (1.0f / WCNT));
    float m2s   = -2.0f * scale;
    float cbase = 1152.0f * scale + bias[k];

    int pw[9];
    #pragma unroll
    for (int t = 0; t < 9; t++)
        pw[t] = __popc(wq[t].x) + __popc(wq[t].y) + __popc(wq[t].z) + __popc(wq[t].w);
    int cs0 = pw[0] + pw[3] + pw[6];
    int cs2 = pw[2] + pw[5] + pw[8];
    int rterm = 0, cc0 = 0, cc2 = 0;
    if (h == 0)        { rterm = 2*(pw[0]+pw[1]+pw[2]) - 384; cc0 = 128 - 2*pw[0]; cc2 = 128 - 2*pw[2]; }
    else if (h == HH-1){ rterm = 2*(pw[6]+pw[7]+pw[8]) - 384; cc0 = 128 - 2*pw[6]; cc2 = 128 - 2*pw[8]; }
    float CB  = cbase + scale * (float)rterm;
    float F0  = CB + scale * (float)(2*cs0 - 384 + cc0);
    float F55 = CB + scale * (float)(2*cs2 - 384 + cc2);

    float* sb = &sbuf[l * 10];
    int fbase = (l >> 2) * 10 + (l & 3) * 2;          // sbuf read base for FLUSH
    // 4 output row-base pointers (r = k sub-block of 16)
    float* o0 = out + ((size_t)(n * KOUT + kg * 64 + (l >> 2)) * HWS + h * WW + (l & 3) * 2);
    float* o1 = o0 + (size_t)16 * HWS;
    float* o2 = o1 + (size_t)16 * HWS;
    float* o3 = o2 + (size_t)16 * HWS;

#define T4(a, q, wt) a += __popc((q).x^(wt).x) + __popc((q).y^(wt).y) + __popc((q).z^(wt).z) + __popc((q).w^(wt).w);
#define FLUSH(C) { \
    *(float2*)(o0 + (C) * 8) = *(float2*)&sbuf[fbase];       \
    *(float2*)(o1 + (C) * 8) = *(float2*)&sbuf[fbase + 160]; \
    *(float2*)(o2 + (C) * 8) = *(float2*)&sbuf[fbase + 320]; \
    *(float2*)(o3 + (C) * 8) = *(float2*)&sbuf[fbase + 480]; \
}
// Body J (w = 8i+1+J): consume slots J,J+1,J+2 (mod 4) = rw w-1,w,w+1;
// then prefetch rw w+3 into slot J%4 (first consumer: body J+2).
#define CORE(J) \
    int a0 = 0, a1 = 0, a2 = 0; \
    T4(a0, xs[(J)&3][0], wq[0]) T4(a0, xs[((J)+1)&3][0], wq[1]) T4(a0, xs[((J)+2)&3][0], wq[2]) \
    T4(a1, xs[(J)&3][1], wq[3]) T4(a1, xs[((J)+1)&3][1], wq[4]) T4(a1, xs[((J)+2)&3][1], wq[5]) \
    T4(a2, xs[(J)&3][2], wq[6]) T4(a2, xs[((J)+1)&3][2], wq[7]) T4(a2, xs[((J)+2)&3][2], wq[8])
#define BODY(J)   { CORE(J) PF((J)&3, (J)+4) sb[((J)+1)&7] = fmaf(m2s, (float)(a0+a1+a2), CB); }
#define BODYNP(J) { CORE(J) sb[((J)+1)&7] = fmaf(m2s, (float)(a0+a1+a2), CB); }

    // w = 0 edge: rw0 (slot0) x wq[1,4,7], rw1 (slot1) x wq[2,5,8], pad col = cs0
    {
        int a0 = cs0, a1 = 0, a2 = 0;
        T4(a0, xs[0][0], wq[1]) T4(a0, xs[1][0], wq[2])
        T4(a1, xs[0][1], wq[4]) T4(a1, xs[1][1], wq[5])
        T4(a2, xs[0][2], wq[7]) T4(a2, xs[1][2], wq[8])
        sb[0] = fmaf(m2s, (float)(a0 + a1 + a2), F0);
    }

    // interior w = 1..48: 6 iters x 8 bodies; PB base = column rw 8i
    {
        const uint4* PB = P;
        #pragma unroll 1
        for (int i = 0; i < 6; i++) {
            BODY(0) BODY(1) BODY(2) BODY(3) BODY(4) BODY(5)
            BODY(6)            // w = 8i+7 writes sb[7]
            FLUSH(i)
            BODY(7)            // w = 8i+8 writes sb[0] (next group)
            PB += 8;
        }
        // peel w = 49..54 (PB at rw 48): prefetches cover rw 52..55 then stop
        BODY(0) BODY(1) BODY(2) BODY(3) BODYNP(4) BODYNP(5)
    }

    // w = 55 edge: rw54 (slot2) x wq[0,3,6], rw55 (slot3) x wq[1,4,7], pad col = cs2
    {
        int a0 = cs2, a1 = 0, a2 = 0;
        T4(a0, xs[2][0], wq[0]) T4(a0, xs[3][0], wq[1])
        T4(a1, xs[2][1], wq[3]) T4(a1, xs[3][1], wq[4])
        T4(a2, xs[2][2], wq[6]) T4(a2, xs[3][2], wq[7])
        sb[7] = fmaf(m2s, (float)(a0 + a1 + a2), F55);
        FLUSH(6)
    }
}

extern "C" void kernel_launch(void* const* d_in, const int* in_sizes, int n_in,
                              void* d_out, int out_size, void* d_ws, size_t ws_size,
                              hipStream_t stream) {
    const float* x    = (const float*)d_in[0];
    const float* wgt  = (const float*)d_in[1];
    const float* bias = (const float*)d_in[2];
    float* out = (float*)d_out;

    // ws: sums (256B) | xpad 32*58*56 uint4 (1.59MB) | wpackT 2304 uint4 (36KB)
    float* sums   = (float*)d_ws;
    uint4* xpad   = (uint4*)((char*)d_ws + 256);
    uint4* wpackT = (uint4*)((char*)d_ws + 256 + (size_t)NB * PADH * WW * 16);

    hipLaunchKernelGGL(init_kernel, dim3(14), dim3(256), 0, stream, xpad, sums);
    hipLaunchKernelGGL(pack_w_kernel, dim3(36), dim3(256), 0, stream, wgt, (uint32_t*)wpackT, sums);
    hipLaunchKernelGGL(pack_x_kernel, dim3(4 * NHW / 256), dim3(256), 0, stream, x, (uint32_t*)xpad, sums);
    hipLaunchKernelGGL(conv_kernel, dim3(NB * HH * 4), dim3(64), 0, stream, xpad, wpackT, sums, bias, out);
}